// Round 1
// baseline (370.119 us; speedup 1.0000x reference)
//
#include <hip/hip_runtime.h>
#include <math.h>

// Problem constants
#define BB 8
#define LL 512
#define HH 768
#define PP 5
#define MM 32
#define DD 256
#define BL (BB*LL)          // 4096 rows
#define NCAT (3*HH)         // 2304 GEMM output cols
#define NSC (LL*PP)         // 2560 scores per batch

// ---------------------------------------------------------------------------
// lengths + n_valid per batch
__global__ __launch_bounds__(256) void prep_lengths(const int* __restrict__ mask,
                                                    int* __restrict__ lengths,
                                                    int* __restrict__ nvalid) {
    int b = blockIdx.x;
    int t = threadIdx.x;
    int v = mask[b*LL + t] + mask[b*LL + 256 + t];
    #pragma unroll
    for (int off = 32; off; off >>= 1) v += __shfl_xor(v, off);
    __shared__ int red[4];
    if ((t & 63) == 0) red[t >> 6] = v;
    __syncthreads();
    if (t == 0) {
        int len = red[0] + red[1] + red[2] + red[3];
        lengths[b] = len;
        int nv = 0;
        #pragma unroll
        for (int p = 0; p < PP; ++p) nv += (len - p > 0) ? (len - p) : 0;
        nvalid[b] = nv;
    }
}

// ---------------------------------------------------------------------------
// Wcat[k][n] (768 x 2304): [A | B | C] where
//   A = W1[0:768]   - W1[2304:3072]   (applied to start)
//   B = W1[768:1536]+ W1[2304:3072]   (applied to end)
//   C = W1[1536:2304]                 (applied to mean)
__global__ __launch_bounds__(256) void build_wcat(const float* __restrict__ W1,
                                                  float* __restrict__ Wcat) {
    int idx = blockIdx.x * 256 + threadIdx.x;
    if (idx >= HH * NCAT) return;
    int k = idx / NCAT, n = idx % NCAT;
    float v;
    if (n < HH) {
        v = W1[(size_t)k*HH + n] - W1[(size_t)(2304 + k)*HH + n];
    } else if (n < 2*HH) {
        int c = n - HH;
        v = W1[(size_t)(768 + k)*HH + c] + W1[(size_t)(2304 + k)*HH + c];
    } else {
        int c = n - 2*HH;
        v = W1[(size_t)(1536 + k)*HH + c];
    }
    Wcat[idx] = v;
}

// ---------------------------------------------------------------------------
// fp32 GEMM: X(4096x768) @ Wcat(768x2304) -> XO(4096x2304)
// 128x128 tile, 256 threads, 8x8 per thread (4x4 quadrants), BK=16
__global__ __launch_bounds__(256) void gemm_kernel(const float* __restrict__ A,
                                                   const float* __restrict__ Bm,
                                                   float* __restrict__ C) {
    __shared__ __align__(16) float As[16][132];   // k-major, padded
    __shared__ __align__(16) float Bs[16][132];
    const int tid = threadIdx.x;
    const int m0 = blockIdx.x * 128;
    const int n0 = blockIdx.y * 128;
    const int tm = tid >> 4;        // 0..15
    const int tn = tid & 15;        // 0..15
    // A staging: row ar (and ar+64), 4 k's at ak
    const int ar = tid >> 2;        // 0..63
    const int ak = (tid & 3) << 2;  // 0,4,8,12
    // B staging: row bk (and bk+8), 4 n's at bn
    const int bk = tid >> 5;        // 0..7
    const int bn = (tid & 31) << 2; // 0..124

    float acc[8][8];
    #pragma unroll
    for (int i = 0; i < 8; ++i)
        #pragma unroll
        for (int j = 0; j < 8; ++j) acc[i][j] = 0.f;

    const float* Abase = A + (size_t)m0 * HH;

    for (int kt = 0; kt < HH; kt += 16) {
        float4 av0 = *(const float4*)(Abase + (size_t)ar * HH + kt + ak);
        float4 av1 = *(const float4*)(Abase + (size_t)(ar + 64) * HH + kt + ak);
        float4 bv0 = *(const float4*)(Bm + (size_t)(kt + bk) * NCAT + n0 + bn);
        float4 bv1 = *(const float4*)(Bm + (size_t)(kt + bk + 8) * NCAT + n0 + bn);
        __syncthreads();
        As[ak+0][ar] = av0.x; As[ak+1][ar] = av0.y; As[ak+2][ar] = av0.z; As[ak+3][ar] = av0.w;
        As[ak+0][ar+64] = av1.x; As[ak+1][ar+64] = av1.y; As[ak+2][ar+64] = av1.z; As[ak+3][ar+64] = av1.w;
        *(float4*)&Bs[bk][bn]   = bv0;
        *(float4*)&Bs[bk+8][bn] = bv1;
        __syncthreads();
        #pragma unroll
        for (int k = 0; k < 16; ++k) {
            float4 a0 = *(const float4*)&As[k][tm*4];
            float4 a1 = *(const float4*)&As[k][64 + tm*4];
            float4 b0 = *(const float4*)&Bs[k][tn*4];
            float4 b1 = *(const float4*)&Bs[k][64 + tn*4];
            float a[8] = {a0.x,a0.y,a0.z,a0.w,a1.x,a1.y,a1.z,a1.w};
            float b[8] = {b0.x,b0.y,b0.z,b0.w,b1.x,b1.y,b1.z,b1.w};
            #pragma unroll
            for (int i = 0; i < 8; ++i)
                #pragma unroll
                for (int j = 0; j < 8; ++j)
                    acc[i][j] = fmaf(a[i], b[j], acc[i][j]);
        }
    }
    #pragma unroll
    for (int i = 0; i < 8; ++i) {
        int mrow = m0 + ((i < 4) ? (tm*4 + i) : (64 + tm*4 + (i - 4)));
        float4 c0 = make_float4(acc[i][0], acc[i][1], acc[i][2], acc[i][3]);
        float4 c1 = make_float4(acc[i][4], acc[i][5], acc[i][6], acc[i][7]);
        *(float4*)(C + (size_t)mrow * NCAT + n0 + tn*4)      = c0;
        *(float4*)(C + (size_t)mrow * NCAT + n0 + 64 + tn*4) = c1;
    }
}

// ---------------------------------------------------------------------------
// scores(b,l,p) = w2 . relu(XA[l] + XB[l+p] + (sum_{t=l..l+p} Y[t])/(p+1) + b1) + b2
// one wave per (b,l); invalid -> -inf
__global__ __launch_bounds__(256) void score_kernel(const float* __restrict__ XO,
                                                    const float* __restrict__ b1,
                                                    const float* __restrict__ w2,
                                                    const float* __restrict__ b2,
                                                    const int* __restrict__ lengths,
                                                    float* __restrict__ sc) {
    int wid = (blockIdx.x * blockDim.x + threadIdx.x) >> 6;  // 0..4095
    int lane = threadIdx.x & 63;
    int b = wid >> 9, l = wid & (LL - 1);
    int len = lengths[b];
    float b2v = b2[0];

    const float* rowXA = XO + (size_t)wid * NCAT;
    float xa[12], sv[12], w2v[12];
    #pragma unroll
    for (int seg = 0; seg < 3; ++seg) {
        int h = seg * 256 + lane * 4;
        float4 a  = *(const float4*)(rowXA + h);
        float4 bb = *(const float4*)(b1 + h);
        float4 w  = *(const float4*)(w2 + h);
        xa[seg*4+0] = a.x + bb.x; xa[seg*4+1] = a.y + bb.y;
        xa[seg*4+2] = a.z + bb.z; xa[seg*4+3] = a.w + bb.w;
        w2v[seg*4+0] = w.x; w2v[seg*4+1] = w.y; w2v[seg*4+2] = w.z; w2v[seg*4+3] = w.w;
        sv[seg*4+0] = 0.f; sv[seg*4+1] = 0.f; sv[seg*4+2] = 0.f; sv[seg*4+3] = 0.f;
    }

    for (int p = 0; p < PP; ++p) {
        int j = l + p;
        float res = -INFINITY;
        if (j < len) {  // wave-uniform
            const float* rowj = XO + (size_t)(b * LL + j) * NCAT;
            float rs = 1.0f / (float)(p + 1);
            float part = 0.f;
            #pragma unroll
            for (int seg = 0; seg < 3; ++seg) {
                int h = seg * 256 + lane * 4;
                float4 xb = *(const float4*)(rowj + HH + h);
                float4 yv = *(const float4*)(rowj + 2*HH + h);
                sv[seg*4+0] += yv.x; sv[seg*4+1] += yv.y;
                sv[seg*4+2] += yv.z; sv[seg*4+3] += yv.w;
                float xbv[4] = {xb.x, xb.y, xb.z, xb.w};
                #pragma unroll
                for (int q = 0; q < 4; ++q) {
                    float pre = xa[seg*4+q] + xbv[q] + sv[seg*4+q] * rs;
                    part += fmaxf(pre, 0.f) * w2v[seg*4+q];
                }
            }
            #pragma unroll
            for (int off = 32; off; off >>= 1) part += __shfl_xor(part, off);
            res = part + b2v;
        }
        if (lane == 0) sc[(size_t)wid * PP + p] = res;
    }
}

// ---------------------------------------------------------------------------
// top-32 per batch, descending score, lower index on ties (jax.lax.top_k)
__global__ __launch_bounds__(256) void topk_kernel(const float* __restrict__ sc,
                                                   int* __restrict__ top_idx,
                                                   float* __restrict__ top_scores) {
    int b = blockIdx.x;
    int tid = threadIdx.x;
    __shared__ float s[NSC];
    __shared__ unsigned long long wbest[4];
    for (int i = tid; i < NSC; i += 256) s[i] = sc[(size_t)b * NSC + i];
    __syncthreads();
    for (int m = 0; m < MM; ++m) {
        unsigned long long best = 0ull;
        for (int i = tid; i < NSC; i += 256) {
            unsigned u = __float_as_uint(s[i]);
            u = (u & 0x80000000u) ? ~u : (u | 0x80000000u);
            unsigned long long key = ((unsigned long long)u << 32) | (unsigned)(0xFFFFFFFFu - i);
            if (key > best) best = key;
        }
        #pragma unroll
        for (int off = 32; off; off >>= 1) {
            unsigned long long o = __shfl_xor(best, off);
            if (o > best) best = o;
        }
        if ((tid & 63) == 0) wbest[tid >> 6] = best;
        __syncthreads();
        if (tid == 0) {
            unsigned long long k0 = wbest[0];
            if (wbest[1] > k0) k0 = wbest[1];
            if (wbest[2] > k0) k0 = wbest[2];
            if (wbest[3] > k0) k0 = wbest[3];
            int idx = (int)(0xFFFFFFFFu - (unsigned)(k0 & 0xFFFFFFFFull));
            top_idx[b * MM + m] = idx;
            top_scores[b * MM + m] = s[idx];
            s[idx] = -INFINITY;
        }
        __syncthreads();
    }
}

// ---------------------------------------------------------------------------
// gathered mean features for selected phrases (direct <=5-row sum)
__global__ __launch_bounds__(256) void feats_kernel(const float* __restrict__ hidden,
                                                    const int* __restrict__ top_idx,
                                                    const int* __restrict__ nvalid,
                                                    float* __restrict__ feats) {
    int bm = blockIdx.x;            // 0..255
    int b = bm >> 5, m = bm & 31;
    int idx = top_idx[bm];
    int l = idx / PP, p = idx % PP;
    bool maskon = (m < nvalid[b]);
    float rs = 1.0f / (float)(p + 1);
    for (int h = threadIdx.x; h < HH; h += 256) {
        float sum = 0.f;
        if (maskon) {
            for (int t = l; t <= l + p; ++t)
                sum += hidden[((size_t)b * LL + t) * HH + h];
            sum *= rs;
        }
        feats[(size_t)bm * HH + h] = sum;
    }
}

// ---------------------------------------------------------------------------
// gate[b,m] = wg2 . tanh(feat @ Wg1 + bg1) + bg2
__global__ __launch_bounds__(256) void gate_kernel(const float* __restrict__ feats,
                                                   const float* __restrict__ Wg1,
                                                   const float* __restrict__ bg1,
                                                   const float* __restrict__ wg2,
                                                   const float* __restrict__ bg2,
                                                   float* __restrict__ gate) {
    int bm = blockIdx.x;
    int tid = threadIdx.x;
    __shared__ float f[HH];
    __shared__ float red[4];
    for (int h = tid; h < HH; h += 256) f[h] = feats[(size_t)bm * HH + h];
    __syncthreads();
    float part = 0.f;
    for (int g = tid; g < HH/2; g += 256) {
        float acc = bg1[g];
        #pragma unroll 8
        for (int k = 0; k < HH; ++k)
            acc = fmaf(f[k], Wg1[(size_t)k * (HH/2) + g], acc);
        part += tanhf(acc) * wg2[g];
    }
    #pragma unroll
    for (int off = 32; off; off >>= 1) part += __shfl_xor(part, off);
    if ((tid & 63) == 0) red[tid >> 6] = part;
    __syncthreads();
    if (tid == 0) gate[bm] = red[0] + red[1] + red[2] + red[3] + bg2[0];
}

// ---------------------------------------------------------------------------
// embeds[b,m,:] = feat @ Wp + bp   (D=256 = one thread per d)
__global__ __launch_bounds__(256) void embed_kernel(const float* __restrict__ feats,
                                                    const float* __restrict__ Wp,
                                                    const float* __restrict__ bp,
                                                    float* __restrict__ out_embeds) {
    int bm = blockIdx.x;
    int d = threadIdx.x;
    __shared__ float f[HH];
    for (int h = threadIdx.x; h < HH; h += 256) f[h] = feats[(size_t)bm * HH + h];
    __syncthreads();
    float acc = bp[d];
    #pragma unroll 8
    for (int k = 0; k < HH; ++k)
        acc = fmaf(f[k], Wp[(size_t)k * DD + d], acc);
    out_embeds[(size_t)bm * DD + d] = acc;
}

// ---------------------------------------------------------------------------
// masks, masked softmax of gate, masked scores
__global__ __launch_bounds__(64) void finalize_kernel(const float* __restrict__ gate,
                                                      const float* __restrict__ top_scores,
                                                      const int* __restrict__ nvalid,
                                                      float* __restrict__ out_masks,
                                                      float* __restrict__ out_attn,
                                                      float* __restrict__ out_scores) {
    int b = blockIdx.x;
    int t = threadIdx.x;
    bool live = (t < MM);
    bool maskon = live && (t < nvalid[b]);
    float g = maskon ? gate[b * MM + t] : -INFINITY;
    float mx = g;
    #pragma unroll
    for (int off = 16; off; off >>= 1) mx = fmaxf(mx, __shfl_xor(mx, off));
    float e = (g == -INFINITY) ? 0.f : expf(g - mx);
    float ssum = e;
    #pragma unroll
    for (int off = 16; off; off >>= 1) ssum += __shfl_xor(ssum, off);
    if (live) {
        out_masks[b * MM + t]  = maskon ? 1.0f : 0.0f;
        out_attn[b * MM + t]   = e / ssum;
        out_scores[b * MM + t] = maskon ? top_scores[b * MM + t] : -INFINITY;
    }
}

// ---------------------------------------------------------------------------
extern "C" void kernel_launch(void* const* d_in, const int* in_sizes, int n_in,
                              void* d_out, int out_size, void* d_ws, size_t ws_size,
                              hipStream_t stream) {
    const float* hidden = (const float*)d_in[0];
    const int*   amask  = (const int*)  d_in[1];
    const float* W1     = (const float*)d_in[2];
    const float* b1     = (const float*)d_in[3];
    const float* w2     = (const float*)d_in[4];
    const float* b2     = (const float*)d_in[5];
    const float* Wg1    = (const float*)d_in[6];
    const float* bg1    = (const float*)d_in[7];
    const float* wg2    = (const float*)d_in[8];
    const float* bg2    = (const float*)d_in[9];
    const float* Wp     = (const float*)d_in[10];
    const float* bp     = (const float*)d_in[11];

    float* out = (float*)d_out;
    float* out_embeds = out;                       // 8*32*256 = 65536
    float* out_masks  = out + 65536;               // 256
    float* out_attn   = out + 65792;               // 256
    float* out_scores = out + 66048;               // 256

    // workspace layout (floats)
    float* wsf    = (float*)d_ws;
    float* Wcat   = wsf;                                   // 768*2304   = 1769472
    float* XO     = Wcat + (size_t)HH * NCAT;              // 4096*2304  = 9437184
    float* scbuf  = XO + (size_t)BL * NCAT;                // 8*2560     = 20480
    float* feats  = scbuf + (size_t)BB * NSC;              // 256*768    = 196608
    float* gate   = feats + (size_t)BB * MM * HH;          // 256
    float* tscore = gate + BB * MM;                        // 256
    int*   tidx    = (int*)(tscore + BB * MM);             // 256
    int*   lengths = tidx + BB * MM;                       // 8
    int*   nvalid  = lengths + BB;                         // 8

    prep_lengths<<<BB, 256, 0, stream>>>(amask, lengths, nvalid);

    {
        int total = HH * NCAT;
        build_wcat<<<(total + 255) / 256, 256, 0, stream>>>(W1, Wcat);
    }

    {
        dim3 grid(BL / 128, NCAT / 128);   // 32 x 18
        gemm_kernel<<<grid, 256, 0, stream>>>(hidden, Wcat, XO);
    }

    score_kernel<<<(BL * 64) / 256, 256, 0, stream>>>(XO, b1, w2, b2, lengths, scbuf);

    topk_kernel<<<BB, 256, 0, stream>>>(scbuf, tidx, tscore);

    feats_kernel<<<BB * MM, 256, 0, stream>>>(hidden, tidx, nvalid, feats);

    gate_kernel<<<BB * MM, 256, 0, stream>>>(feats, Wg1, bg1, wg2, bg2, gate);

    embed_kernel<<<BB * MM, 256, 0, stream>>>(feats, Wp, bp, out_embeds);

    finalize_kernel<<<BB, 64, 0, stream>>>(gate, tscore, nvalid, out_masks, out_attn, out_scores);
}

// Round 2
// 270.071 us; speedup vs baseline: 1.3705x; 1.3705x over previous
//
#include <hip/hip_runtime.h>
#include <math.h>

// Problem constants
#define BB 8
#define LL 512
#define HH 768
#define PP 5
#define MM 32
#define DD 256
#define BL (BB*LL)          // 4096 rows
#define NCAT (3*HH)         // 2304 GEMM output cols
#define NSC (LL*PP)         // 2560 scores per batch
#define GK HH               // per-term K = 768

typedef short short8_t __attribute__((ext_vector_type(8)));
typedef float floatx4  __attribute__((ext_vector_type(4)));

// ---------------------------------------------------------------------------
// bf16 helpers (RNE)
__device__ __forceinline__ unsigned short f2bf_rne(float x) {
    unsigned u = __float_as_uint(x);
    unsigned r = u + 0x7FFFu + ((u >> 16) & 1u);
    return (unsigned short)(r >> 16);
}
__device__ __forceinline__ void split3(float x, unsigned short& s0,
                                       unsigned short& s1, unsigned short& s2) {
    unsigned short h0 = f2bf_rne(x);
    float f0 = __uint_as_float((unsigned)h0 << 16);
    float r1 = x - f0;
    unsigned short h1 = f2bf_rne(r1);
    float f1 = __uint_as_float((unsigned)h1 << 16);
    float r2 = r1 - f1;
    unsigned short h2 = f2bf_rne(r2);
    s0 = h0; s1 = h1; s2 = h2;
}

// ---------------------------------------------------------------------------
// lengths + n_valid per batch
__global__ __launch_bounds__(256) void prep_lengths(const int* __restrict__ mask,
                                                    int* __restrict__ lengths,
                                                    int* __restrict__ nvalid) {
    int b = blockIdx.x;
    int t = threadIdx.x;
    int v = mask[b*LL + t] + mask[b*LL + 256 + t];
    #pragma unroll
    for (int off = 32; off; off >>= 1) v += __shfl_xor(v, off);
    __shared__ int red[4];
    if ((t & 63) == 0) red[t >> 6] = v;
    __syncthreads();
    if (t == 0) {
        int len = red[0] + red[1] + red[2] + red[3];
        lengths[b] = len;
        int nv = 0;
        #pragma unroll
        for (int p = 0; p < PP; ++p) nv += (len - p > 0) ? (len - p) : 0;
        nvalid[b] = nv;
    }
}

// ---------------------------------------------------------------------------
// A-splits: hidden (4096x768 f32) -> Aspl[3][4096][768] bf16
__global__ __launch_bounds__(256) void build_asplit(const float* __restrict__ hidden,
                                                    unsigned short* __restrict__ Aspl) {
    const size_t PLANE = (size_t)BL * GK;
    size_t base = ((size_t)blockIdx.x * 256 + threadIdx.x) * 4;
    float4 v = *(const float4*)(hidden + base);
    ushort4 p0, p1, p2;
    split3(v.x, p0.x, p1.x, p2.x);
    split3(v.y, p0.y, p1.y, p2.y);
    split3(v.z, p0.z, p1.z, p2.z);
    split3(v.w, p0.w, p1.w, p2.w);
    *(ushort4*)(Aspl + base)             = p0;
    *(ushort4*)(Aspl + PLANE + base)     = p1;
    *(ushort4*)(Aspl + 2 * PLANE + base) = p2;
}

// ---------------------------------------------------------------------------
// B-splits, TRANSPOSED: Bspl[3][2304 n][768 k] bf16, built directly from W1.
// Wcat[k][n]: n<768:   W1[k][n] - W1[2304+k][n]        (start coeff)
//             n<1536:  W1[768+k][c] + W1[2304+k][c]    (end coeff)
//             else:    W1[1536+k][c]                   (mean coeff)
__global__ __launch_bounds__(256) void build_bsplit(const float* __restrict__ W1,
                                                    unsigned short* __restrict__ Bspl) {
    const size_t PLANE = (size_t)NCAT * GK;
    __shared__ float wv[16][65];
    int n0 = blockIdx.x * 16;
    int k0 = blockIdx.y * 64;
    int tx = threadIdx.x & 15;   // n offset (coalesced W1 read)
    int ty = threadIdx.x >> 4;   // k-quad
    int n = n0 + tx;
    #pragma unroll
    for (int j = 0; j < 4; ++j) {
        int k = k0 + ty * 4 + j;
        float w;
        if (n < HH) {
            w = W1[(size_t)k * HH + n] - W1[(size_t)(3*HH + k) * HH + n];
        } else if (n < 2 * HH) {
            int c = n - HH;
            w = W1[(size_t)(HH + k) * HH + c] + W1[(size_t)(3*HH + k) * HH + c];
        } else {
            int c = n - 2 * HH;
            w = W1[(size_t)(2*HH + k) * HH + c];
        }
        wv[tx][ty * 4 + j] = w;
    }
    __syncthreads();
    int n2 = threadIdx.x >> 4;   // 0..15
    int kq = threadIdx.x & 15;   // 0..15 (coalesced Bspl write)
    unsigned short e0[4], e1[4], e2[4];
    #pragma unroll
    for (int j = 0; j < 4; ++j)
        split3(wv[n2][kq * 4 + j], e0[j], e1[j], e2[j]);
    size_t off = (size_t)(n0 + n2) * GK + k0 + kq * 4;
    *(ushort4*)(Bspl + off)             = make_ushort4(e0[0], e0[1], e0[2], e0[3]);
    *(ushort4*)(Bspl + PLANE + off)     = make_ushort4(e1[0], e1[1], e1[2], e1[3]);
    *(ushort4*)(Bspl + 2 * PLANE + off) = make_ushort4(e2[0], e2[1], e2[2], e2[3]);
}

// ---------------------------------------------------------------------------
// bf16x3-split MFMA GEMM: XO = sum over 6 term-products of Aspl x Bspl^T
// 128x128 tile, BK=64, 4 waves (2x2 of 64x64), mfma_f32_16x16x32_bf16.
// LDS tiles [128 rows][64 k] bf16 (128B rows), XOR slot-swizzle slot^(row&7);
// staged via global_load_lds w=16 with pre-swizzled GLOBAL source (linear LDS).
__global__ __launch_bounds__(256) void gemm_mfma(const unsigned short* __restrict__ Aspl,
                                                 const unsigned short* __restrict__ Bspl,
                                                 float* __restrict__ C) {
    __shared__ __align__(16) unsigned short Asm[128 * 64];
    __shared__ __align__(16) unsigned short Bsm[128 * 64];
    const int tid  = threadIdx.x;
    const int wave = tid >> 6;
    const int lane = tid & 63;
    const int m0 = blockIdx.x * 128;
    const int n0 = blockIdx.y * 128;
    const int wr = wave >> 1;            // 0..1
    const int wc = wave & 1;             // 0..1
    const int srow = lane >> 3;          // 0..7 (row within 8-row stage group)
    const int slog = (lane & 7) ^ srow;  // logical k-slot this lane must fetch
    const int l15 = lane & 15;
    const int g   = lane >> 4;           // 0..3
    const int r7  = l15 & 7;

    floatx4 acc[4][4];
    #pragma unroll
    for (int i = 0; i < 4; ++i)
        #pragma unroll
        for (int j = 0; j < 4; ++j) acc[i][j] = (floatx4)0.f;

    const size_t APL = (size_t)BL * GK;
    const size_t BPL = (size_t)NCAT * GK;

    #pragma unroll 1
    for (int t = 0; t < 6; ++t) {
        // term selects: ai = {0,0,1,1,0,2}, bi = {0,1,0,1,2,0} (no arrays: rule #20)
        const int a_sel = (t < 4) ? (t >> 1) : ((t == 4) ? 0 : 2);
        const int b_sel = (t < 4) ? (t & 1)  : ((t == 4) ? 2 : 0);
        const unsigned short* Ab = Aspl + (size_t)a_sel * APL + (size_t)m0 * GK;
        const unsigned short* Bb = Bspl + (size_t)b_sel * BPL + (size_t)n0 * GK;
        #pragma unroll 1
        for (int kt = 0; kt < GK; kt += 64) {
            __syncthreads();   // previous compute done before overwrite
            #pragma unroll
            for (int j = 0; j < 4; ++j) {
                int base_r = (j * 4 + wave) * 8;
                const unsigned short* sa = Ab + (size_t)(base_r + srow) * GK + kt + slog * 8;
                __builtin_amdgcn_global_load_lds(
                    (const __attribute__((address_space(1))) void*)sa,
                    (__attribute__((address_space(3))) void*)&Asm[base_r * 64],
                    16, 0, 0);
                const unsigned short* sb = Bb + (size_t)(base_r + srow) * GK + kt + slog * 8;
                __builtin_amdgcn_global_load_lds(
                    (const __attribute__((address_space(1))) void*)sb,
                    (__attribute__((address_space(3))) void*)&Bsm[base_r * 64],
                    16, 0, 0);
            }
            __syncthreads();   // compiler drains vmcnt(0) before this barrier
            #pragma unroll
            for (int ks = 0; ks < 2; ++ks) {
                const int sph = ((ks * 4 + g) ^ r7) * 8;
                short8_t afr[4], bfr[4];
                #pragma unroll
                for (int mf = 0; mf < 4; ++mf)
                    afr[mf] = *(const short8_t*)&Asm[(wr * 64 + mf * 16 + l15) * 64 + sph];
                #pragma unroll
                for (int nf = 0; nf < 4; ++nf)
                    bfr[nf] = *(const short8_t*)&Bsm[(wc * 64 + nf * 16 + l15) * 64 + sph];
                #pragma unroll
                for (int mf = 0; mf < 4; ++mf)
                    #pragma unroll
                    for (int nf = 0; nf < 4; ++nf)
                        acc[mf][nf] = __builtin_amdgcn_mfma_f32_16x16x32_bf16(
                            afr[mf], bfr[nf], acc[mf][nf], 0, 0, 0);
            }
        }
    }
    // epilogue: D row = (lane>>4)*4 + reg, col = lane&15 (m89-verified layout)
    #pragma unroll
    for (int mf = 0; mf < 4; ++mf) {
        #pragma unroll
        for (int nf = 0; nf < 4; ++nf) {
            int col  = n0 + wc * 64 + nf * 16 + l15;
            int rowb = m0 + wr * 64 + mf * 16 + g * 4;
            #pragma unroll
            for (int e = 0; e < 4; ++e)
                C[(size_t)(rowb + e) * NCAT + col] = acc[mf][nf][e];
        }
    }
}

// ---------------------------------------------------------------------------
// scores(b,l,p) = w2 . relu(XA[l] + XB[l+p] + (sum_{t=l..l+p} Y[t])/(p+1) + b1) + b2
// one wave per (b,l); invalid -> -inf
__global__ __launch_bounds__(256) void score_kernel(const float* __restrict__ XO,
                                                    const float* __restrict__ b1,
                                                    const float* __restrict__ w2,
                                                    const float* __restrict__ b2,
                                                    const int* __restrict__ lengths,
                                                    float* __restrict__ sc) {
    int wid = (blockIdx.x * blockDim.x + threadIdx.x) >> 6;  // 0..4095
    int lane = threadIdx.x & 63;
    int b = wid >> 9, l = wid & (LL - 1);
    int len = lengths[b];
    float b2v = b2[0];

    const float* rowXA = XO + (size_t)wid * NCAT;
    float xa[12], sv[12], w2v[12];
    #pragma unroll
    for (int seg = 0; seg < 3; ++seg) {
        int h = seg * 256 + lane * 4;
        float4 a  = *(const float4*)(rowXA + h);
        float4 bb = *(const float4*)(b1 + h);
        float4 w  = *(const float4*)(w2 + h);
        xa[seg*4+0] = a.x + bb.x; xa[seg*4+1] = a.y + bb.y;
        xa[seg*4+2] = a.z + bb.z; xa[seg*4+3] = a.w + bb.w;
        w2v[seg*4+0] = w.x; w2v[seg*4+1] = w.y; w2v[seg*4+2] = w.z; w2v[seg*4+3] = w.w;
        sv[seg*4+0] = 0.f; sv[seg*4+1] = 0.f; sv[seg*4+2] = 0.f; sv[seg*4+3] = 0.f;
    }

    for (int p = 0; p < PP; ++p) {
        int j = l + p;
        float res = -INFINITY;
        if (j < len) {  // wave-uniform
            const float* rowj = XO + (size_t)(b * LL + j) * NCAT;
            float rs = 1.0f / (float)(p + 1);
            float part = 0.f;
            #pragma unroll
            for (int seg = 0; seg < 3; ++seg) {
                int h = seg * 256 + lane * 4;
                float4 xb = *(const float4*)(rowj + HH + h);
                float4 yv = *(const float4*)(rowj + 2*HH + h);
                sv[seg*4+0] += yv.x; sv[seg*4+1] += yv.y;
                sv[seg*4+2] += yv.z; sv[seg*4+3] += yv.w;
                float xbv[4] = {xb.x, xb.y, xb.z, xb.w};
                #pragma unroll
                for (int q = 0; q < 4; ++q) {
                    float pre = xa[seg*4+q] + xbv[q] + sv[seg*4+q] * rs;
                    part += fmaxf(pre, 0.f) * w2v[seg*4+q];
                }
            }
            #pragma unroll
            for (int off = 32; off; off >>= 1) part += __shfl_xor(part, off);
            res = part + b2v;
        }
        if (lane == 0) sc[(size_t)wid * PP + p] = res;
    }
}

// ---------------------------------------------------------------------------
// top-32 per batch, descending score, lower index on ties (jax.lax.top_k)
__global__ __launch_bounds__(256) void topk_kernel(const float* __restrict__ sc,
                                                   int* __restrict__ top_idx,
                                                   float* __restrict__ top_scores) {
    int b = blockIdx.x;
    int tid = threadIdx.x;
    __shared__ float s[NSC];
    __shared__ unsigned long long wbest[4];
    for (int i = tid; i < NSC; i += 256) s[i] = sc[(size_t)b * NSC + i];
    __syncthreads();
    for (int m = 0; m < MM; ++m) {
        unsigned long long best = 0ull;
        for (int i = tid; i < NSC; i += 256) {
            unsigned u = __float_as_uint(s[i]);
            u = (u & 0x80000000u) ? ~u : (u | 0x80000000u);
            unsigned long long key = ((unsigned long long)u << 32) | (unsigned)(0xFFFFFFFFu - i);
            if (key > best) best = key;
        }
        #pragma unroll
        for (int off = 32; off; off >>= 1) {
            unsigned long long o = __shfl_xor(best, off);
            if (o > best) best = o;
        }
        if ((tid & 63) == 0) wbest[tid >> 6] = best;
        __syncthreads();
        if (tid == 0) {
            unsigned long long k0 = wbest[0];
            if (wbest[1] > k0) k0 = wbest[1];
            if (wbest[2] > k0) k0 = wbest[2];
            if (wbest[3] > k0) k0 = wbest[3];
            int idx = (int)(0xFFFFFFFFu - (unsigned)(k0 & 0xFFFFFFFFull));
            top_idx[b * MM + m] = idx;
            top_scores[b * MM + m] = s[idx];
            s[idx] = -INFINITY;
        }
        __syncthreads();
    }
}

// ---------------------------------------------------------------------------
// gathered mean features for selected phrases (direct <=5-row sum)
__global__ __launch_bounds__(256) void feats_kernel(const float* __restrict__ hidden,
                                                    const int* __restrict__ top_idx,
                                                    const int* __restrict__ nvalid,
                                                    float* __restrict__ feats) {
    int bm = blockIdx.x;            // 0..255
    int b = bm >> 5, m = bm & 31;
    int idx = top_idx[bm];
    int l = idx / PP, p = idx % PP;
    bool maskon = (m < nvalid[b]);
    float rs = 1.0f / (float)(p + 1);
    for (int h = threadIdx.x; h < HH; h += 256) {
        float sum = 0.f;
        if (maskon) {
            for (int t = l; t <= l + p; ++t)
                sum += hidden[((size_t)b * LL + t) * HH + h];
            sum *= rs;
        }
        feats[(size_t)bm * HH + h] = sum;
    }
}

// ---------------------------------------------------------------------------
// gate[b,m] = wg2 . tanh(feat @ Wg1 + bg1) + bg2
__global__ __launch_bounds__(256) void gate_kernel(const float* __restrict__ feats,
                                                   const float* __restrict__ Wg1,
                                                   const float* __restrict__ bg1,
                                                   const float* __restrict__ wg2,
                                                   const float* __restrict__ bg2,
                                                   float* __restrict__ gate) {
    int bm = blockIdx.x;
    int tid = threadIdx.x;
    __shared__ float f[HH];
    __shared__ float red[4];
    for (int h = tid; h < HH; h += 256) f[h] = feats[(size_t)bm * HH + h];
    __syncthreads();
    float part = 0.f;
    for (int g = tid; g < HH/2; g += 256) {
        float acc = bg1[g];
        #pragma unroll 8
        for (int k = 0; k < HH; ++k)
            acc = fmaf(f[k], Wg1[(size_t)k * (HH/2) + g], acc);
        part += tanhf(acc) * wg2[g];
    }
    #pragma unroll
    for (int off = 32; off; off >>= 1) part += __shfl_xor(part, off);
    if ((tid & 63) == 0) red[tid >> 6] = part;
    __syncthreads();
    if (tid == 0) gate[bm] = red[0] + red[1] + red[2] + red[3] + bg2[0];
}

// ---------------------------------------------------------------------------
// embeds[b,m,:] = feat @ Wp + bp   (D=256 = one thread per d)
__global__ __launch_bounds__(256) void embed_kernel(const float* __restrict__ feats,
                                                    const float* __restrict__ Wp,
                                                    const float* __restrict__ bp,
                                                    float* __restrict__ out_embeds) {
    int bm = blockIdx.x;
    int d = threadIdx.x;
    __shared__ float f[HH];
    for (int h = threadIdx.x; h < HH; h += 256) f[h] = feats[(size_t)bm * HH + h];
    __syncthreads();
    float acc = bp[d];
    #pragma unroll 8
    for (int k = 0; k < HH; ++k)
        acc = fmaf(f[k], Wp[(size_t)k * DD + d], acc);
    out_embeds[(size_t)bm * DD + d] = acc;
}

// ---------------------------------------------------------------------------
// masks, masked softmax of gate, masked scores
__global__ __launch_bounds__(64) void finalize_kernel(const float* __restrict__ gate,
                                                      const float* __restrict__ top_scores,
                                                      const int* __restrict__ nvalid,
                                                      float* __restrict__ out_masks,
                                                      float* __restrict__ out_attn,
                                                      float* __restrict__ out_scores) {
    int b = blockIdx.x;
    int t = threadIdx.x;
    bool live = (t < MM);
    bool maskon = live && (t < nvalid[b]);
    float g = maskon ? gate[b * MM + t] : -INFINITY;
    float mx = g;
    #pragma unroll
    for (int off = 16; off; off >>= 1) mx = fmaxf(mx, __shfl_xor(mx, off));
    float e = (g == -INFINITY) ? 0.f : expf(g - mx);
    float ssum = e;
    #pragma unroll
    for (int off = 16; off; off >>= 1) ssum += __shfl_xor(ssum, off);
    if (live) {
        out_masks[b * MM + t]  = maskon ? 1.0f : 0.0f;
        out_attn[b * MM + t]   = e / ssum;
        out_scores[b * MM + t] = maskon ? top_scores[b * MM + t] : -INFINITY;
    }
}

// ---------------------------------------------------------------------------
extern "C" void kernel_launch(void* const* d_in, const int* in_sizes, int n_in,
                              void* d_out, int out_size, void* d_ws, size_t ws_size,
                              hipStream_t stream) {
    const float* hidden = (const float*)d_in[0];
    const int*   amask  = (const int*)  d_in[1];
    const float* W1     = (const float*)d_in[2];
    const float* b1     = (const float*)d_in[3];
    const float* w2     = (const float*)d_in[4];
    const float* b2     = (const float*)d_in[5];
    const float* Wg1    = (const float*)d_in[6];
    const float* bg1    = (const float*)d_in[7];
    const float* wg2    = (const float*)d_in[8];
    const float* bg2    = (const float*)d_in[9];
    const float* Wp     = (const float*)d_in[10];
    const float* bp     = (const float*)d_in[11];

    float* out = (float*)d_out;
    float* out_embeds = out;                       // 8*32*256 = 65536
    float* out_masks  = out + 65536;               // 256
    float* out_attn   = out + 65792;               // 256
    float* out_scores = out + 66048;               // 256

    // workspace layout
    unsigned short* Aspl = (unsigned short*)d_ws;              // 3*4096*768 us = 18.9 MB
    unsigned short* Bspl = Aspl + (size_t)3 * BL * GK;         // 3*2304*768 us = 10.6 MB
    float* XO     = (float*)(Bspl + (size_t)3 * NCAT * GK);    // 4096*2304 f32 = 37.7 MB
    float* scbuf  = XO + (size_t)BL * NCAT;                    // 8*2560
    float* feats  = scbuf + (size_t)BB * NSC;                  // 256*768
    float* gate   = feats + (size_t)BB * MM * HH;              // 256
    float* tscore = gate + BB * MM;                            // 256
    int*   tidx    = (int*)(tscore + BB * MM);                 // 256
    int*   lengths = tidx + BB * MM;                           // 8
    int*   nvalid  = lengths + BB;                             // 8

    prep_lengths<<<BB, 256, 0, stream>>>(amask, lengths, nvalid);

    build_asplit<<<(BL * GK / 4) / 256, 256, 0, stream>>>(hidden, Aspl);

    {
        dim3 grid(NCAT / 16, GK / 64);   // 144 x 12
        build_bsplit<<<grid, 256, 0, stream>>>(W1, Bspl);
    }

    {
        dim3 grid(BL / 128, NCAT / 128);   // 32 x 18
        gemm_mfma<<<grid, 256, 0, stream>>>(Aspl, Bspl, XO);
    }

    score_kernel<<<(BL * 64) / 256, 256, 0, stream>>>(XO, b1, w2, b2, lengths, scbuf);

    topk_kernel<<<BB, 256, 0, stream>>>(scbuf, tidx, tscore);

    feats_kernel<<<BB * MM, 256, 0, stream>>>(hidden, tidx, nvalid, feats);

    gate_kernel<<<BB * MM, 256, 0, stream>>>(feats, Wg1, bg1, wg2, bg2, gate);

    embed_kernel<<<BB * MM, 256, 0, stream>>>(feats, Wp, bp, out_embeds);

    finalize_kernel<<<BB, 64, 0, stream>>>(gate, tscore, nvalid, out_masks, out_attn, out_scores);
}